// Round 1
// 332.253 us; speedup vs baseline: 1.1152x; 1.1152x over previous
//
#include <hip/hip_runtime.h>

// Problem constants
#define Cn   192      // channels = 3*D
#define Dn   64       // hidden
#define G3   192      // 3*D gates
#define HWn  16384    // H*W per batch
#define NSp  131072L  // B*H*W total spatial
#define Tn   128

typedef unsigned short u16;
typedef __attribute__((ext_vector_type(8))) short s8v;   // 8 bf16 (4 VGPRs) MFMA A/B frag
typedef __attribute__((ext_vector_type(4))) float f4v;   // MFMA C/D frag

__device__ __forceinline__ float bf2f(u16 u){
  union { unsigned int i; float f; } v; v.i = ((unsigned int)u) << 16; return v.f;
}
__device__ __forceinline__ u16 f2bf(float f){
  union { float f; unsigned int u; } v; v.f = f;
  return (u16)((v.u + 0x7FFFu + ((v.u >> 16) & 1u)) >> 16);  // RNE
}
__device__ __forceinline__ s8v load8_f32_as_bf16(const float* __restrict__ p){
  s8v r;
  #pragma unroll
  for (int i = 0; i < 8; i++) r[i] = (short)f2bf(p[i]);
  return r;
}
// fast transcendentals (avoid precise-div sequences; ~1ulp is far below bf16 noise)
__device__ __forceinline__ float ex2f(float x){
#if __has_builtin(__builtin_amdgcn_exp2f)
  return __builtin_amdgcn_exp2f(x);
#else
  float r; asm("v_exp_f32 %0, %1" : "=v"(r) : "v"(x)); return r;
#endif
}
__device__ __forceinline__ float rcpa(float x){
#if __has_builtin(__builtin_amdgcn_rcpf)
  return __builtin_amdgcn_rcpf(x);
#else
  float r; asm("v_rcp_f32 %0, %1" : "=v"(r) : "v"(x)); return r;
#endif
}

// gate-group scale folded into weights: r,z: -log2(e)  (sigmoid(x)=rcp(1+exp2(-log2e*x)))
//                                       n:   -2log2(e) (tanh(y)=2*rcp(1+exp2(-2log2e*y))-1)
#define SC_RZ (-1.4426950408889634f)
#define SC_N  (-2.8853900817779268f)

// ---------------------------------------------------------------------------
// Kernel 0: W_comb = W_ih @ Wi  (store bf16, gate-scaled), b_comb = W_ih @ bi + b_ih (fp32, scaled)
// ---------------------------------------------------------------------------
__global__ __launch_bounds__(256) void k_wcomb(const float* __restrict__ Wi, const float* __restrict__ bi,
                                               const float* __restrict__ W_ih, const float* __restrict__ b_ih,
                                               u16* __restrict__ wcomb, float* __restrict__ bcomb){
  if (blockIdx.x < 144) {
    int idx = blockIdx.x * 256 + threadIdx.x;   // 36864 = 192*192
    int g = idx / 192, c = idx - g * 192;
    float acc = 0.f;
    #pragma unroll 8
    for (int d = 0; d < 64; d++)
      acc += W_ih[g * 64 + d] * Wi[d * 192 + c];
    float sc = (g >= 128) ? SC_N : SC_RZ;
    wcomb[g * 192 + c] = f2bf(sc * acc);
  } else if (threadIdx.x < 192) {
    int g = threadIdx.x;
    float acc = b_ih[g];
    for (int d = 0; d < 64; d++)
      acc += W_ih[g * 64 + d] * bi[d];
    float sc = (g >= 128) ? SC_N : SC_RZ;
    bcomb[g] = sc * acc;
  }
}

// ---------------------------------------------------------------------------
// Kernel 1: G[s][g] = b_comb[g] + sum_c x[c][s] * W_comb[g][c]   (bf16 out, pre-scaled)
// ---------------------------------------------------------------------------
__global__ __launch_bounds__(256) void k_gates(const float* __restrict__ x, const u16* __restrict__ wcomb,
                                               const float* __restrict__ bcomb, u16* __restrict__ G){
  __shared__ u16 xT[64][200];                 // [spatial][channel], row = 400 B (16B-aligned, padded)
  const int tid = threadIdx.x;
  const int wave = tid >> 6, lane = tid & 63;
  const int col = lane & 15, kq = lane >> 4;
  const long s0 = (long)blockIdx.x * 64;
  const int b   = (int)(s0 >> 14);
  const int hw0 = (int)(s0 & 16383);

  // B-fragments: wave handles gates [48w, 48w+48): 3 n-tiles x 6 k-chunks
  s8v bfrag[3][6];
  #pragma unroll
  for (int j = 0; j < 3; j++) {
    int g = wave * 48 + j * 16 + col;
    #pragma unroll
    for (int kc = 0; kc < 6; kc++)
      bfrag[j][kc] = *(const s8v*)(wcomb + g * 192 + kc * 32 + kq * 8);
  }

  // Stage x tile transposed: float4 (4 consecutive spatial) per iter, cvt bf16
  for (int idx = tid; idx < 192 * 16; idx += 256) {
    int c  = idx >> 4;
    int s4 = (idx & 15) * 4;
    float4 v = *(const float4*)(x + (long)(b * 192 + c) * HWn + hw0 + s4);
    xT[s4 + 0][c] = f2bf(v.x); xT[s4 + 1][c] = f2bf(v.y);
    xT[s4 + 2][c] = f2bf(v.z); xT[s4 + 3][c] = f2bf(v.w);
  }
  __syncthreads();

  f4v acc[4][3];
  #pragma unroll
  for (int m = 0; m < 4; m++)
    #pragma unroll
    for (int j = 0; j < 3; j++) acc[m][j] = (f4v){0.f, 0.f, 0.f, 0.f};

  #pragma unroll
  for (int kc = 0; kc < 6; kc++) {
    #pragma unroll
    for (int m = 0; m < 4; m++) {
      s8v a = *(const s8v*)(&xT[m * 16 + col][kc * 32 + kq * 8]);
      #pragma unroll
      for (int j = 0; j < 3; j++)
        acc[m][j] = __builtin_amdgcn_mfma_f32_16x16x32_bf16(a, bfrag[j][kc], acc[m][j], 0, 0, 0);
    }
  }

  // Epilogue: bias + store (C layout: col=lane&15 -> gate, row=4*kq+reg -> spatial)
  #pragma unroll
  for (int j = 0; j < 3; j++) {
    int g = wave * 48 + j * 16 + col;
    float bias = bcomb[g];
    #pragma unroll
    for (int m = 0; m < 4; m++) {
      #pragma unroll
      for (int r = 0; r < 4; r++) {
        long srow = s0 + m * 16 + kq * 4 + r;
        G[srow * 192 + g] = f2bf(acc[m][j][r] + bias);
      }
    }
  }
}

// ---------------------------------------------------------------------------
// Kernel 2: directional GRU scans — swapped-operand MFMA (HG^T = W_hh @ h^T).
// 1 block = 16 sequences; wave w owns d-slice [16w,16w+16).
// k-dim permutation sigma(p=kc*32+kq*8+i) = 16*(2kc+(i>>2)) + 4kq + (i&3)
// makes MFMA output rows (d = 16a+4kq+r) line up exactly with next step's
// B-frag slots -> gate math fully in MFMA output registers; only the 2KB
// h tile crosses LDS (double-buffered, ONE barrier/step, no HG round-trip).
// ---------------------------------------------------------------------------
__global__ __launch_bounds__(256) void k_scan(const u16* __restrict__ G, const float* __restrict__ W_hh,
                                              const float* __restrict__ b_hh, u16* __restrict__ Hall){
  __shared__ u16 ha[2][16][72];   // [buf][seq][d], row 144 B -> 2-way (free) bank aliasing only
  const int tid = threadIdx.x;
  const int w = tid >> 6, lane = tid & 63;
  const int col = lane & 15, kq = lane >> 4;
  const int dir  = blockIdx.x >> 6;   // 0:right 1:down 2:left 3:up
  const int sblk = blockIdx.x & 63;
  const int doff = 16 * w + 4 * kq;   // this lane's 4 d values: doff..doff+3

  // A-frags: W_hh rows g = g3*64 + 16w + col (m=col), k-slots permuted by sigma, scaled.
  s8v afrag[3][2];
  f4v biasf[3];
  #pragma unroll
  for (int g3 = 0; g3 < 3; g3++) {
    float sc = (g3 == 2) ? SC_N : SC_RZ;
    const float* wr = W_hh + (g3 * 64 + 16 * w + col) * 64;
    #pragma unroll
    for (int kc = 0; kc < 2; kc++) {
      s8v f;
      #pragma unroll
      for (int i = 0; i < 4; i++) f[i]     = (short)f2bf(sc * wr[kc * 32 +      4 * kq + i]);
      #pragma unroll
      for (int i = 0; i < 4; i++) f[4 + i] = (short)f2bf(sc * wr[kc * 32 + 16 + 4 * kq + i]);
      afrag[g3][kc] = f;
    }
    const float* bb = b_hh + g3 * 64 + doff;   // rows m = 4kq+r -> bias differs per r
    biasf[g3] = (f4v){ sc * bb[0], sc * bb[1], sc * bb[2], sc * bb[3] };
  }

  // this lane's sequence (shared by the 4 kq sub-lanes at same col)
  const int seq = sblk * 16 + col;             // 0..1023
  const int b = seq >> 7, a = seq & 127;
  long base; int stride;
  if ((dir & 1) == 0) { base = ((long)(b * 128 + a)) * 128; stride = 1;   } // scan over w
  else                { base = (long)b * 16384 + a;         stride = 128; } // scan over h
  const int rev = dir >> 1;
  u16* __restrict__ Hs = Hall + (long)dir * (NSp * 64);

  for (int i = tid; i < 2 * 16 * 72; i += 256) ((u16*)ha)[i] = 0;   // h0 = 0
  float hold[4] = {0.f, 0.f, 0.f, 0.f};

  // prefetch xg for t=0 (already gate-scaled in G)
  uint2 xr, xz, xn;
  {
    int tp = rev ? 127 : 0;
    const u16* gp = G + (base + (long)tp * stride) * 192 + doff;
    xr = *(const uint2*)(gp);
    xz = *(const uint2*)(gp + 64);
    xn = *(const uint2*)(gp + 128);
  }
  __syncthreads();

  int p = 0;
  for (int t = 0; t < 128; t++) {
    // prefetch xg for t+1 (hidden under this step's MFMA+gate)
    uint2 nxr, nxz, nxn;
    if (t < 127) {
      int tp2 = rev ? (126 - t) : (t + 1);
      const u16* gp2 = G + (base + (long)tp2 * stride) * 192 + doff;
      nxr = *(const uint2*)(gp2);
      nxz = *(const uint2*)(gp2 + 64);
      nxn = *(const uint2*)(gp2 + 128);
    }

    // B-frags (n=col=seq) from ha[p], sigma-permuted k order
    union BU { ushort4 q[2]; s8v v; } u0, u1;
    u0.q[0] = *(const ushort4*)(&ha[p][col][ 0 + 4 * kq]);
    u0.q[1] = *(const ushort4*)(&ha[p][col][16 + 4 * kq]);
    u1.q[0] = *(const ushort4*)(&ha[p][col][32 + 4 * kq]);
    u1.q[1] = *(const ushort4*)(&ha[p][col][48 + 4 * kq]);

    // HG^T tiles: D[m=gate 16w+4kq+r within group][n=seq=col], bias preloaded
    f4v acc0 = biasf[0], acc1 = biasf[1], acc2 = biasf[2];
    acc0 = __builtin_amdgcn_mfma_f32_16x16x32_bf16(afrag[0][0], u0.v, acc0, 0, 0, 0);
    acc1 = __builtin_amdgcn_mfma_f32_16x16x32_bf16(afrag[1][0], u0.v, acc1, 0, 0, 0);
    acc2 = __builtin_amdgcn_mfma_f32_16x16x32_bf16(afrag[2][0], u0.v, acc2, 0, 0, 0);
    acc0 = __builtin_amdgcn_mfma_f32_16x16x32_bf16(afrag[0][1], u1.v, acc0, 0, 0, 0);
    acc1 = __builtin_amdgcn_mfma_f32_16x16x32_bf16(afrag[1][1], u1.v, acc1, 0, 0, 0);
    acc2 = __builtin_amdgcn_mfma_f32_16x16x32_bf16(afrag[2][1], u1.v, acc2, 0, 0, 0);

    // gate phase — entirely in this lane's registers
    u16* px = (u16*)&xr; u16* pz = (u16*)&xz; u16* pn = (u16*)&xn;
    ushort4 hv; u16* hvp = (u16*)&hv;
    #pragma unroll
    for (int r = 0; r < 4; r++) {
      float rr = rcpa(1.f + ex2f(bf2f(px[r]) + acc0[r]));          // sigmoid (scale folded)
      float zz = rcpa(1.f + ex2f(bf2f(pz[r]) + acc1[r]));
      float nn = 2.f * rcpa(1.f + ex2f(bf2f(pn[r]) + rr * acc2[r])) - 1.f;  // tanh
      float h  = nn + zz * (hold[r] - nn);
      hold[r] = h;
      hvp[r] = f2bf(h);
    }

    *(ushort4*)(&ha[p ^ 1][col][doff]) = hv;             // h for next step (other buffer)
    long posc = base + (long)(rev ? (127 - t) : t) * stride;
    *(ushort4*)(Hs + posc * 64 + doff) = hv;             // stream h out
    if (t < 127) { xr = nxr; xz = nxz; xn = nxn; }
    __syncthreads();                                     // single barrier per step
    p ^= 1;
  }
}

// ---------------------------------------------------------------------------
// Kernel 3: out[b,c,h,w] = bo[c] + Wo[c,:] . (sum_dirs h)/4   (fp32 out)
// ---------------------------------------------------------------------------
__global__ __launch_bounds__(256) void k_out(const u16* __restrict__ Hall, const float* __restrict__ Wo,
                                             const float* __restrict__ bo, float* __restrict__ out){
  __shared__ u16 hs4[64][72];
  const int tid = threadIdx.x;
  const int wave = tid >> 6, lane = tid & 63;
  const int col = lane & 15, kq = lane >> 4;
  const long s0 = (long)blockIdx.x * 64;
  const int b   = (int)(s0 >> 14);
  const int hw0 = (int)(s0 & 16383);

  s8v bfrag[3][2]; f4v biasf[3];
  #pragma unroll
  for (int j = 0; j < 3; j++) {
    int g = wave * 48 + j * 16 + col;
    bfrag[j][0] = load8_f32_as_bf16(Wo + g * 64 + kq * 8);
    bfrag[j][1] = load8_f32_as_bf16(Wo + g * 64 + 32 + kq * 8);
    float bb = bo[g];
    biasf[j] = (f4v){bb, bb, bb, bb};
  }

  // Stage (sum of 4 direction h)/4 as bf16
  for (int idx = tid; idx < 64 * 16; idx += 256) {
    int sl = idx >> 4;
    int d4 = (idx & 15) * 4;
    long p = (s0 + sl) * 64 + d4;
    float a0 = 0.f, a1 = 0.f, a2 = 0.f, a3 = 0.f;
    #pragma unroll
    for (int dd = 0; dd < 4; dd++) {
      uint2 v = *(const uint2*)(Hall + dd * (NSp * 64) + p);
      u16* pv = (u16*)&v;
      a0 += bf2f(pv[0]); a1 += bf2f(pv[1]); a2 += bf2f(pv[2]); a3 += bf2f(pv[3]);
    }
    ushort4 o;
    o.x = f2bf(0.25f * a0); o.y = f2bf(0.25f * a1);
    o.z = f2bf(0.25f * a2); o.w = f2bf(0.25f * a3);
    *(ushort4*)(&hs4[sl][d4]) = o;
  }
  __syncthreads();

  f4v acc[4][3];
  #pragma unroll
  for (int m = 0; m < 4; m++)
    #pragma unroll
    for (int j = 0; j < 3; j++) acc[m][j] = biasf[j];

  #pragma unroll
  for (int kc = 0; kc < 2; kc++) {
    #pragma unroll
    for (int m = 0; m < 4; m++) {
      s8v a = *(const s8v*)(&hs4[m * 16 + col][kc * 32 + kq * 8]);
      #pragma unroll
      for (int j = 0; j < 3; j++)
        acc[m][j] = __builtin_amdgcn_mfma_f32_16x16x32_bf16(a, bfrag[j][kc], acc[m][j], 0, 0, 0);
    }
  }

  #pragma unroll
  for (int j = 0; j < 3; j++) {
    int g = wave * 48 + j * 16 + col;
    #pragma unroll
    for (int m = 0; m < 4; m++) {
      float4 v;
      v.x = acc[m][j][0]; v.y = acc[m][j][1];
      v.z = acc[m][j][2]; v.w = acc[m][j][3];
      long addr = ((long)(b * 192 + g) << 14) + hw0 + m * 16 + kq * 4;
      *(float4*)(out + addr) = v;
    }
  }
}

// ---------------------------------------------------------------------------
extern "C" void kernel_launch(void* const* d_in, const int* in_sizes, int n_in,
                              void* d_out, int out_size, void* d_ws, size_t ws_size,
                              hipStream_t stream){
  const float* x    = (const float*)d_in[0];
  const float* Wi   = (const float*)d_in[1];
  const float* bi   = (const float*)d_in[2];
  const float* W_ih = (const float*)d_in[3];
  const float* W_hh = (const float*)d_in[4];
  const float* b_ih = (const float*)d_in[5];
  const float* b_hh = (const float*)d_in[6];
  const float* Wo   = (const float*)d_in[7];
  const float* bo   = (const float*)d_in[8];

  char* ws = (char*)d_ws;
  u16*   wcomb = (u16*)(ws);                       // 192*192 bf16        = 73728 B
  float* bcomb = (float*)(ws + 73728);             // 192 fp32            = 768 B
  u16*   G     = (u16*)(ws + 74496);               // 131072*192 bf16     = 50331648 B
  u16*   Hall  = (u16*)(ws + 50406144);            // 4*131072*64 bf16    = 67108864 B
                                                   // total               = 117515008 B

  k_wcomb<<<145,  256, 0, stream>>>(Wi, bi, W_ih, b_ih, wcomb, bcomb);
  k_gates<<<2048, 256, 0, stream>>>(x, wcomb, bcomb, G);
  k_scan <<<256,  256, 0, stream>>>(G, W_hh, b_hh, Hall);
  k_out  <<<2048, 256, 0, stream>>>(Hall, Wo, bo, (float*)d_out);
}